// Round 2
// baseline (357.035 us; speedup 1.0000x reference)
//
#include <hip/hip_runtime.h>
#include <hip/hip_bf16.h>
#include <cstdint>

#define B_ 16
#define N_ 1024
#define D_ 256
#define H_ 128

typedef unsigned short u16;
typedef __attribute__((ext_vector_type(8))) short bf16x8;
typedef __attribute__((ext_vector_type(4))) float f32x4;

__device__ __forceinline__ u16 f2bf(float f) {
    union { float f; uint32_t u; } v; v.f = f;
    return (u16)((v.u + 0x7FFFu + ((v.u >> 16) & 1u)) >> 16);  // RNE
}

typedef __attribute__((address_space(3))) void lds_void;
typedef const __attribute__((address_space(1))) void g_void;

__device__ __forceinline__ void gl_lds16(const void* g, void* l) {
    // async global->LDS, 16B/lane; LDS dest = wave-uniform base + lane*16
    __builtin_amdgcn_global_load_lds((g_void*)g, (lds_void*)l, 16, 0, 0);
}

// ---------------------------------------------------------------------------
// K1: fp32 adjacencies -> bf16 (normal + transposed copies). Run once.
// grid (N/32, N/32, B*2), block 256. Pure streaming (no reuse) -> no swizzle.
__global__ __launch_bounds__(256) void k_conv_adj(
    const float* __restrict__ dep, const float* __restrict__ lat,
    u16* __restrict__ depb, u16* __restrict__ latb,
    u16* __restrict__ depTb, u16* __restrict__ latTb)
{
    __shared__ float tile[32][33];
    const int bz = blockIdx.z;
    const int b = bz >> 1;
    const float* src = (bz & 1) ? lat : dep;
    u16* dstN = (bz & 1) ? latb : depb;
    u16* dstT = (bz & 1) ? latTb : depTb;
    const int r0 = blockIdx.y * 32, c0 = blockIdx.x * 32;
    const int t = threadIdx.x;
    const int r = t >> 3, cg = (t & 7) * 4;

    const float4 v = *(const float4*)(src + ((size_t)b * N_ + r0 + r) * N_ + c0 + cg);
    ushort4 nv;
    nv.x = f2bf(v.x); nv.y = f2bf(v.y); nv.z = f2bf(v.z); nv.w = f2bf(v.w);
    *(ushort4*)(dstN + ((size_t)b * N_ + r0 + r) * N_ + c0 + cg) = nv;

    tile[r][cg] = v.x; tile[r][cg + 1] = v.y; tile[r][cg + 2] = v.z; tile[r][cg + 3] = v.w;
    __syncthreads();

    const int orow = t >> 3, ii = (t & 7) * 4;  // out row = source col
    ushort4 tv;
    tv.x = f2bf(tile[ii][orow]);     tv.y = f2bf(tile[ii + 1][orow]);
    tv.z = f2bf(tile[ii + 2][orow]); tv.w = f2bf(tile[ii + 3][orow]);
    *(ushort4*)(dstT + ((size_t)b * N_ + c0 + orow) * N_ + r0 + ii) = tv;
}

// ---------------------------------------------------------------------------
// K2: per-layer refine gate + x transposed to bf16 [B, D, N].
// grid (N/32, B+4), block 256. y >= B slices convert the layer's FC weights
// (exactly 4*32*256 = H*D threads), removing the separate k_convw launch.
__global__ __launch_bounds__(256) void k_gate_xt(
    const float* __restrict__ x, const float* __restrict__ rg,
    float* __restrict__ gate, u16* __restrict__ xT,
    const float* __restrict__ wi, const float* __restrict__ wo,
    u16* __restrict__ wib, u16* __restrict__ wob)
{
    if (blockIdx.y >= B_) {
        const int i = ((blockIdx.y - B_) * 32 + blockIdx.x) * 256 + threadIdx.x;
        wib[i] = f2bf(wi[i]);
        wob[i] = f2bf(wo[i]);
        return;
    }

    __shared__ u16 lx[D_][36];     // [d][n], pad to 36 for 8B-aligned rows
    __shared__ float srg[D_];
    const int b = blockIdx.y, n0 = blockIdx.x * 32;
    const int t = threadIdx.x;
    srg[t] = rg[t];
    __syncthreads();

    const int r = t >> 3, cg = t & 7;  // row r (0..31), 8 threads/row
    const float* xrow = x + ((size_t)b * N_ + n0 + r) * D_;
    float dot = 0.f;
    #pragma unroll
    for (int u = 0; u < 8; ++u) {
        const int c = cg * 32 + u * 4;
        const float4 v = *(const float4*)(xrow + c);
        lx[c][r] = f2bf(v.x); lx[c + 1][r] = f2bf(v.y);
        lx[c + 2][r] = f2bf(v.z); lx[c + 3][r] = f2bf(v.w);
        dot += v.x * srg[c] + v.y * srg[c + 1] + v.z * srg[c + 2] + v.w * srg[c + 3];
    }
    dot += __shfl_down(dot, 4, 8);
    dot += __shfl_down(dot, 2, 8);
    dot += __shfl_down(dot, 1, 8);
    if (cg == 0) gate[(size_t)b * N_ + n0 + r] = 1.f / (1.f + expf(-dot));
    __syncthreads();

    #pragma unroll
    for (int i = 0; i < 8; ++i) {
        const int unit = i * 256 + t;
        const int d = unit >> 3, nch = (unit & 7) * 4;
        ushort4 wv;
        wv.x = lx[d][nch];     wv.y = lx[d][nch + 1];
        wv.z = lx[d][nch + 2]; wv.w = lx[d][nch + 3];
        *(ushort4*)(xT + ((size_t)b * D_ + d) * N_ + n0 + nch) = wv;
    }
}

// ---------------------------------------------------------------------------
// K3: dual-A MFMA GEMM: Ax = g*(A1@x) + (1-g)*(A2@x), then gcn-gate + x.
// z=0: (dep,lat,Wgi,bgi)->axin ; z=1: (depT,latT,Wgo,bgo)->axout
// Flat grid 1024, block 256 (4 waves). Tile 32 rows x 256 cols, BK=32.
// XCD-bijective swizzle: each XCD owns 2 full batches -> xT panel L2-resident.
// Double-buffered staging, one barrier per K-step.
// LDS exactly 40960B (4 blocks/CU = 163840B = full pool); launch_bounds(256,4)
// caps VGPR at 128 for full residency (1024 blocks = exactly 4/CU, no tail).
__global__ __launch_bounds__(256, 4) void k_gemm_ax(
    const u16* __restrict__ depb, const u16* __restrict__ latb,
    const u16* __restrict__ depTb, const u16* __restrict__ latTb,
    const u16* __restrict__ xT,
    const float* __restrict__ gate,
    const float* __restrict__ Wgi, const float* __restrict__ Wgo,
    const float* __restrict__ bgi, const float* __restrict__ bgo,
    const float* __restrict__ xcur,
    u16* __restrict__ axin, u16* __restrict__ axout)
{
    // 2 x 20KB staging buffers; epilogue aliases [32][260] f32 (33280B);
    // sh_g/sh_s live in the dead tail (touched only after staging drains).
    __shared__ __align__(16) char smem[40960];
    float* hbuf = (float*)smem;
    float* sh_g = (float*)(smem + 33536);
    float* sh_s = (float*)(smem + 33664);

    // bijective XCD swizzle: nwg=1024, cpx=128; XCD k gets logical 128k..128k+127
    const int bid = blockIdx.x;
    const int logical = (bid & 7) * 128 + (bid >> 3);
    const int b = logical >> 6;          // 0..15 (2 batches per XCD)
    const int rem = logical & 63;
    const int z = rem >> 5;
    const int m0 = (rem & 31) * 32;

    const u16* A1 = z ? depTb : depb;
    const u16* A2 = z ? latTb : latb;
    const float* Wg = z ? Wgo : Wgi;
    const float bg0 = z ? bgo[0] : bgi[0];
    u16* outp = z ? axout : axin;

    const int t = threadIdx.x;
    const int lane = t & 63;
    const int w = t >> 6;

    f32x4 acc1[2][4], acc2[2][4];
    const f32x4 fz = {0.f, 0.f, 0.f, 0.f};
    #pragma unroll
    for (int i = 0; i < 2; ++i)
        #pragma unroll
        for (int j = 0; j < 4; ++j) { acc1[i][j] = fz; acc2[i][j] = fz; }

    // 20 x 1KB staging chunks, 5 per wave; loff = u16 offset within a buffer
    const u16* gsrc[5];
    int loff[5];
    #pragma unroll
    for (int ci = 0; ci < 5; ++ci) {
        const int c = w * 5 + ci;
        const int el = lane * 8;
        if (c < 4) {
            const int cc = c & 1;
            const int e = cc * 512 + el;
            const int m = e >> 5, k = e & 31;
            const u16* base = (c < 2) ? A1 : A2;
            gsrc[ci] = base + ((size_t)b * N_ + m0 + m) * N_ + k;
            loff[ci] = ((c < 2) ? 0 : 1024) + cc * 512;
        } else {
            const int cc = c - 4;
            const int e = cc * 512 + el;
            const int n = e >> 5, k = e & 31;
            gsrc[ci] = xT + ((size_t)b * D_ + n) * N_ + k;
            loff[ci] = 2048 + cc * 512;
        }
    }

    u16* const sb0 = (u16*)smem;          // buffer 0: [sA1|sA2|sB] = 10240 u16
    u16* const sb1 = sb0 + 10240;         // buffer 1

    // prologue: stage K-tile 0 into buffer 0
    #pragma unroll
    for (int ci = 0; ci < 5; ++ci) gl_lds16(gsrc[ci], sb0 + loff[ci]);
    #pragma unroll
    for (int ci = 0; ci < 5; ++ci) gsrc[ci] += 32;

    const int mrow = lane & 15;
    const int kg = (lane >> 4) * 8;

    for (int ks = 0; ks < N_ / 32; ++ks) {
        __syncthreads();  // drains prev stage (vmcnt) + prev reads (lgkm)
        const u16* sc = (ks & 1) ? sb1 : sb0;
        u16* sn = (ks & 1) ? sb0 : sb1;
        if (ks < N_ / 32 - 1) {
            #pragma unroll
            for (int ci = 0; ci < 5; ++ci) gl_lds16(gsrc[ci], sn + loff[ci]);
            #pragma unroll
            for (int ci = 0; ci < 5; ++ci) gsrc[ci] += 32;
        }
        const u16* sA1 = sc;
        const u16* sA2 = sc + 1024;
        const u16* sB  = sc + 2048;
        bf16x8 a1[2], a2[2], fb[4];
        #pragma unroll
        for (int mt = 0; mt < 2; ++mt) {
            a1[mt] = *(const bf16x8*)(sA1 + (mt * 16 + mrow) * 32 + kg);
            a2[mt] = *(const bf16x8*)(sA2 + (mt * 16 + mrow) * 32 + kg);
        }
        #pragma unroll
        for (int nt = 0; nt < 4; ++nt)
            fb[nt] = *(const bf16x8*)(sB + (w * 64 + nt * 16 + mrow) * 32 + kg);
        #pragma unroll
        for (int mt = 0; mt < 2; ++mt)
            #pragma unroll
            for (int nt = 0; nt < 4; ++nt) {
                acc1[mt][nt] = __builtin_amdgcn_mfma_f32_16x16x32_bf16(a1[mt], fb[nt], acc1[mt][nt], 0, 0, 0);
                acc2[mt][nt] = __builtin_amdgcn_mfma_f32_16x16x32_bf16(a2[mt], fb[nt], acc2[mt][nt], 0, 0, 0);
            }
    }
    __syncthreads();  // all LDS reads done; safe to alias buffers + write tail

    if (t < 32) sh_g[t] = gate[(size_t)b * N_ + m0 + t];
    __syncthreads();  // sh_g visible to the blend below

    // epilogue: gate blend into hbuf (C layout: col=lane&15, row=(lane>>4)*4+reg)
    const int hi = lane >> 4;
    #pragma unroll
    for (int mt = 0; mt < 2; ++mt)
        #pragma unroll
        for (int nt = 0; nt < 4; ++nt) {
            const int col = w * 64 + nt * 16 + mrow;
            #pragma unroll
            for (int rr = 0; rr < 4; ++rr) {
                const int row = mt * 16 + hi * 4 + rr;
                const float g = sh_g[row];
                hbuf[row * 260 + col] = g * acc1[mt][nt][rr] + (1.f - g) * acc2[mt][nt][rr];
            }
        }
    __syncthreads();

    {   // per-row dot with Wg -> sigmoid
        const int rr = t >> 3;
        const int c0 = (t & 7) * 32;
        float dot = 0.f;
        #pragma unroll 8
        for (int u = 0; u < 32; ++u) dot += hbuf[rr * 260 + c0 + u] * Wg[c0 + u];
        dot += __shfl_down(dot, 4, 8);
        dot += __shfl_down(dot, 2, 8);
        dot += __shfl_down(dot, 1, 8);
        if ((t & 7) == 0) sh_s[rr] = 1.f / (1.f + expf(-dot));
    }
    __syncthreads();

    #pragma unroll
    for (int i = 0; i < 16; ++i) {
        const int row = (t >> 7) + i * 2;
        const int c = (t & 127) * 2;
        const float s = sh_s[row];
        const size_t gidx = ((size_t)b * N_ + m0 + row) * D_ + c;
        const float2 xv = *(const float2*)(xcur + gidx);
        const float v0 = hbuf[row * 260 + c] * s + bg0 + xv.x;
        const float v1 = hbuf[row * 260 + c + 1] * s + bg0 + xv.y;
        *(ushort2*)(outp + gidx) = make_ushort2(f2bf(v0), f2bf(v1));
    }
}

// ---------------------------------------------------------------------------
// K4: h = [axin@Wi^T + 2bi, axout@Wo^T + 2bo]; LayerNorm; exact GELU.
// Output is ALWAYS fp32 (reference output dtype is float32).
// grid (N/32, B), block 256. Waves 0,1 -> in-half; 2,3 -> out-half.
// Double-buffered staging, one barrier per K-step (8 K-steps).
__global__ __launch_bounds__(256, 4) void k_fc_ln(
    const u16* __restrict__ axin, const u16* __restrict__ axout,
    const u16* __restrict__ Wib, const u16* __restrict__ Wob,
    const float* __restrict__ bi, const float* __restrict__ bo,
    const float* __restrict__ lg, const float* __restrict__ lb,
    float* __restrict__ outp)
{
    __shared__ __align__(16) char smem[40960];
    float* hbuf = (float*)smem;     // epilogue alias [32][260]
    float* sh_mu = (float*)(smem + 33536);
    float* sh_rs = (float*)(smem + 33664);

    const int b = blockIdx.y, m0 = blockIdx.x * 32;
    const int t = threadIdx.x, lane = t & 63, w = t >> 6;
    const int half = w >> 1, wn = w & 1;

    f32x4 acc[2][4];
    const f32x4 fz = {0.f, 0.f, 0.f, 0.f};
    #pragma unroll
    for (int i = 0; i < 2; ++i)
        #pragma unroll
        for (int j = 0; j < 4; ++j) acc[i][j] = fz;

    // per-buffer layout (u16): sAin 0, sAout 1024, sWi 2048, sWo 6144
    const u16* gsrc[5];
    int loff[5];
    #pragma unroll
    for (int ci = 0; ci < 5; ++ci) {
        const int c = w * 5 + ci;
        const int el = lane * 8;
        if (c < 4) {
            const int cc = c & 1;
            const int e = cc * 512 + el;
            const int m = e >> 5, k = e & 31;
            const u16* base = (c < 2) ? axin : axout;
            gsrc[ci] = base + ((size_t)b * N_ + m0 + m) * D_ + k;
            loff[ci] = ((c < 2) ? 0 : 1024) + cc * 512;
        } else {
            const int cc = (c - 4) & 7;
            const int e = cc * 512 + el;
            const int n = e >> 5, k = e & 31;
            const u16* base = (c < 12) ? Wib : Wob;
            gsrc[ci] = base + (size_t)n * D_ + k;
            loff[ci] = ((c < 12) ? 2048 : 6144) + cc * 512;
        }
    }

    u16* const sb0 = (u16*)smem;
    u16* const sb1 = sb0 + 10240;

    #pragma unroll
    for (int ci = 0; ci < 5; ++ci) gl_lds16(gsrc[ci], sb0 + loff[ci]);
    #pragma unroll
    for (int ci = 0; ci < 5; ++ci) gsrc[ci] += 32;

    const int mrow = lane & 15;
    const int kg = (lane >> 4) * 8;

    for (int ks = 0; ks < D_ / 32; ++ks) {
        __syncthreads();
        const u16* sc = (ks & 1) ? sb1 : sb0;
        u16* sn = (ks & 1) ? sb0 : sb1;
        if (ks < D_ / 32 - 1) {
            #pragma unroll
            for (int ci = 0; ci < 5; ++ci) gl_lds16(gsrc[ci], sn + loff[ci]);
            #pragma unroll
            for (int ci = 0; ci < 5; ++ci) gsrc[ci] += 32;
        }
        const u16* sA = sc + (half ? 1024 : 0);
        const u16* sW = sc + 2048 + (half ? 4096 : 0);
        bf16x8 a[2], fb[4];
        #pragma unroll
        for (int mt = 0; mt < 2; ++mt)
            a[mt] = *(const bf16x8*)(sA + (mt * 16 + mrow) * 32 + kg);
        #pragma unroll
        for (int nt = 0; nt < 4; ++nt)
            fb[nt] = *(const bf16x8*)(sW + (wn * 64 + nt * 16 + mrow) * 32 + kg);
        #pragma unroll
        for (int mt = 0; mt < 2; ++mt)
            #pragma unroll
            for (int nt = 0; nt < 4; ++nt)
                acc[mt][nt] = __builtin_amdgcn_mfma_f32_16x16x32_bf16(a[mt], fb[nt], acc[mt][nt], 0, 0, 0);
    }
    __syncthreads();

    const int hi = lane >> 4;
    #pragma unroll
    for (int mt = 0; mt < 2; ++mt)
        #pragma unroll
        for (int nt = 0; nt < 4; ++nt) {
            const int colh = wn * 64 + nt * 16 + mrow;     // 0..127 within half
            const int col = half * 128 + colh;
            const float bias = 2.f * (half ? bo[colh] : bi[colh]);
            #pragma unroll
            for (int rr = 0; rr < 4; ++rr) {
                const int row = mt * 16 + hi * 4 + rr;
                hbuf[row * 260 + col] = acc[mt][nt][rr] + bias;
            }
        }
    __syncthreads();

    {   // LN stats per row
        const int rr = t >> 3;
        const int c0 = (t & 7) * 32;
        float s = 0.f, ss = 0.f;
        #pragma unroll 8
        for (int u = 0; u < 32; ++u) {
            const float v = hbuf[rr * 260 + c0 + u];
            s += v; ss += v * v;
        }
        s += __shfl_down(s, 4, 8);  ss += __shfl_down(ss, 4, 8);
        s += __shfl_down(s, 2, 8);  ss += __shfl_down(ss, 2, 8);
        s += __shfl_down(s, 1, 8);  ss += __shfl_down(ss, 1, 8);
        if ((t & 7) == 0) {
            const float mu = s * (1.f / 256.f);
            const float var = ss * (1.f / 256.f) - mu * mu;
            sh_mu[rr] = mu;
            sh_rs[rr] = rsqrtf(var + 1e-5f);
        }
    }
    __syncthreads();

    #pragma unroll
    for (int i = 0; i < 16; ++i) {
        const int row = (t >> 7) + i * 2;
        const int c = (t & 127) * 2;
        const float mu = sh_mu[row], rs = sh_rs[row];
        const float2 gg = *(const float2*)(lg + c);
        const float2 bb = *(const float2*)(lb + c);
        const float v0 = (hbuf[row * 260 + c] - mu) * rs * gg.x + bb.x;
        const float v1 = (hbuf[row * 260 + c + 1] - mu) * rs * gg.y + bb.y;
        const float y0 = 0.5f * v0 * (1.f + erff(v0 * 0.70710678118654752f));
        const float y1 = 0.5f * v1 * (1.f + erff(v1 * 0.70710678118654752f));
        const size_t gidx = ((size_t)b * N_ + m0 + row) * D_ + c;
        *(float2*)(outp + gidx) = make_float2(y0, y1);
    }
}

// ---------------------------------------------------------------------------
extern "C" void kernel_launch(void* const* d_in, const int* in_sizes, int n_in,
                              void* d_out, int out_size, void* d_ws, size_t ws_size,
                              hipStream_t stream)
{
    (void)in_sizes; (void)n_in; (void)out_size; (void)ws_size;

    const float* x0  = (const float*)d_in[0];
    const float* lat = (const float*)d_in[1];
    const float* dep = (const float*)d_in[2];
    const float* rg  = (const float*)d_in[3];   // [L,D,1]
    const float* Wgi = (const float*)d_in[4];   // [L,D,1]
    const float* bgi = (const float*)d_in[5];   // [L,1]
    const float* Wgo = (const float*)d_in[6];
    const float* bgo = (const float*)d_in[7];
    const float* fiW = (const float*)d_in[8];   // [L,H,D]
    const float* fib = (const float*)d_in[9];   // [L,H]
    const float* foW = (const float*)d_in[10];
    const float* fob = (const float*)d_in[11];
    const float* lng = (const float*)d_in[12];  // [L,2H]
    const float* lnb = (const float*)d_in[13];

    char* ws = (char*)d_ws;
    size_t off = 0;
    auto alloc = [&](size_t bytes) {
        char* p = ws + off;
        off += (bytes + 255) & ~(size_t)255;
        return p;
    };
    u16* depb  = (u16*)alloc(2ull * B_ * N_ * N_);
    u16* latb  = (u16*)alloc(2ull * B_ * N_ * N_);
    u16* depTb = (u16*)alloc(2ull * B_ * N_ * N_);
    u16* latTb = (u16*)alloc(2ull * B_ * N_ * N_);
    u16* xT    = (u16*)alloc(2ull * B_ * D_ * N_);
    u16* axin  = (u16*)alloc(2ull * B_ * N_ * D_);
    u16* axout = (u16*)alloc(2ull * B_ * N_ * D_);
    float* gate = (float*)alloc(4ull * B_ * N_);
    float* xbuf = (float*)alloc(4ull * B_ * N_ * D_);
    u16* Wib = (u16*)alloc(2ull * H_ * D_);
    u16* Wob = (u16*)alloc(2ull * H_ * D_);

    k_conv_adj<<<dim3(32, 32, 32), 256, 0, stream>>>(dep, lat, depb, latb, depTb, latTb);

    const float* xcur = x0;
    for (int l = 0; l < 2; ++l) {
        k_gate_xt<<<dim3(32, B_ + 4), 256, 0, stream>>>(
            xcur, rg + l * D_, gate, xT,
            fiW + (size_t)l * H_ * D_, foW + (size_t)l * H_ * D_, Wib, Wob);
        k_gemm_ax<<<dim3(1024), 256, 0, stream>>>(
            depb, latb, depTb, latTb, xT, gate,
            Wgi + l * D_, Wgo + l * D_, bgi + l, bgo + l,
            xcur, axin, axout);
        const bool last = (l == 1);
        k_fc_ln<<<dim3(32, B_), 256, 0, stream>>>(
            axin, axout, Wib, Wob,
            fib + l * H_, fob + l * H_,
            lng + l * 2 * H_, lnb + l * 2 * H_,
            last ? (float*)d_out : xbuf);
        xcur = xbuf;
    }
}

// Round 4
// 352.603 us; speedup vs baseline: 1.0126x; 1.0126x over previous
//
#include <hip/hip_runtime.h>
#include <hip/hip_bf16.h>
#include <cstdint>

#define B_ 16
#define N_ 1024
#define D_ 256
#define H_ 128

typedef unsigned short u16;
typedef __attribute__((ext_vector_type(8))) short bf16x8;
typedef __attribute__((ext_vector_type(4))) float f32x4;

__device__ __forceinline__ u16 f2bf(float f) {
    union { float f; uint32_t u; } v; v.f = f;
    return (u16)((v.u + 0x7FFFu + ((v.u >> 16) & 1u)) >> 16);  // RNE
}

typedef __attribute__((address_space(3))) void lds_void;
typedef const __attribute__((address_space(1))) void g_void;

__device__ __forceinline__ void gl_lds16(const void* g, void* l) {
    // async global->LDS, 16B/lane; LDS dest = wave-uniform base + lane*16
    __builtin_amdgcn_global_load_lds((g_void*)g, (lds_void*)l, 16, 0, 0);
}

__device__ __forceinline__ void vm_wait5() { asm volatile("s_waitcnt vmcnt(5)" ::: "memory"); }
__device__ __forceinline__ void vm_wait0() { asm volatile("s_waitcnt vmcnt(0)" ::: "memory"); }

// ---------------------------------------------------------------------------
// K1: fp32 adjacencies -> bf16 (normal + transposed). 64x64 tiles so every
// 4-lane group stores 128B contiguous segments for BOTH outputs.
// grid (16, 16, B*2), block 256.
__global__ __launch_bounds__(256) void k_conv_adj(
    const float* __restrict__ dep, const float* __restrict__ lat,
    u16* __restrict__ depb, u16* __restrict__ latb,
    u16* __restrict__ depTb, u16* __restrict__ latTb)
{
    __shared__ u16 tile[64][64];   // granule-XOR swizzled: col granule g stored at g^(r&7)
    const int bz = blockIdx.z;
    const int b = bz >> 1;
    const float* src = (bz & 1) ? lat : dep;
    u16* dstN = (bz & 1) ? latb : depb;
    u16* dstT = (bz & 1) ? latTb : depTb;
    const int r0 = blockIdx.y * 64, c0 = blockIdx.x * 64;
    const int t = threadIdx.x;
    const int r = t >> 2, cg = (t & 3) * 16;

    const float* srow = src + ((size_t)b * N_ + r0 + r) * N_ + c0 + cg;
    bf16x8 lo, hi;
    {
        const float4 v0 = *(const float4*)(srow);
        const float4 v1 = *(const float4*)(srow + 4);
        const float4 v2 = *(const float4*)(srow + 8);
        const float4 v3 = *(const float4*)(srow + 12);
        lo[0] = (short)f2bf(v0.x); lo[1] = (short)f2bf(v0.y); lo[2] = (short)f2bf(v0.z); lo[3] = (short)f2bf(v0.w);
        lo[4] = (short)f2bf(v1.x); lo[5] = (short)f2bf(v1.y); lo[6] = (short)f2bf(v1.z); lo[7] = (short)f2bf(v1.w);
        hi[0] = (short)f2bf(v2.x); hi[1] = (short)f2bf(v2.y); hi[2] = (short)f2bf(v2.z); hi[3] = (short)f2bf(v2.w);
        hi[4] = (short)f2bf(v3.x); hi[5] = (short)f2bf(v3.y); hi[6] = (short)f2bf(v3.z); hi[7] = (short)f2bf(v3.w);
    }
    u16* nrow = dstN + ((size_t)b * N_ + r0 + r) * N_ + c0 + cg;
    *(bf16x8*)nrow = lo;
    *(bf16x8*)(nrow + 8) = hi;

    const int g0 = (t & 3) * 2;
    const int s = r & 7;
    *(bf16x8*)(&tile[r][((g0    ) ^ s) * 8]) = lo;
    *(bf16x8*)(&tile[r][((g0 + 1) ^ s) * 8]) = hi;
    __syncthreads();

    const int sc = t >> 2, rg2 = (t & 3) * 16;   // out row = source col
    bf16x8 o0, o1;
    #pragma unroll
    for (int i = 0; i < 8; ++i) {
        const int R = rg2 + i;
        o0[i] = (short)tile[R][(((sc >> 3) ^ (R & 7)) * 8) + (sc & 7)];
    }
    #pragma unroll
    for (int i = 0; i < 8; ++i) {
        const int R = rg2 + 8 + i;
        o1[i] = (short)tile[R][(((sc >> 3) ^ (R & 7)) * 8) + (sc & 7)];
    }
    u16* dT = dstT + ((size_t)b * N_ + c0 + sc) * N_ + r0 + rg2;
    *(bf16x8*)dT = o0;
    *(bf16x8*)(dT + 8) = o1;
}

// ---------------------------------------------------------------------------
// K2: per-layer refine gate + x transposed to bf16 [B, D, N].
// grid (N/32, B+4), block 256. y >= B slices convert the layer's FC weights.
__global__ __launch_bounds__(256) void k_gate_xt(
    const float* __restrict__ x, const float* __restrict__ rg,
    float* __restrict__ gate, u16* __restrict__ xT,
    const float* __restrict__ wi, const float* __restrict__ wo,
    u16* __restrict__ wib, u16* __restrict__ wob)
{
    if (blockIdx.y >= B_) {
        const int i = ((blockIdx.y - B_) * 32 + blockIdx.x) * 256 + threadIdx.x;
        wib[i] = f2bf(wi[i]);
        wob[i] = f2bf(wo[i]);
        return;
    }

    __shared__ u16 lx[D_][36];
    __shared__ float srg[D_];
    const int b = blockIdx.y, n0 = blockIdx.x * 32;
    const int t = threadIdx.x;
    srg[t] = rg[t];
    __syncthreads();

    const int r = t >> 3, cg = t & 7;
    const float* xrow = x + ((size_t)b * N_ + n0 + r) * D_;
    float dot = 0.f;
    #pragma unroll
    for (int u = 0; u < 8; ++u) {
        const int c = cg * 32 + u * 4;
        const float4 v = *(const float4*)(xrow + c);
        lx[c][r] = f2bf(v.x); lx[c + 1][r] = f2bf(v.y);
        lx[c + 2][r] = f2bf(v.z); lx[c + 3][r] = f2bf(v.w);
        dot += v.x * srg[c] + v.y * srg[c + 1] + v.z * srg[c + 2] + v.w * srg[c + 3];
    }
    dot += __shfl_down(dot, 4, 8);
    dot += __shfl_down(dot, 2, 8);
    dot += __shfl_down(dot, 1, 8);
    if (cg == 0) gate[(size_t)b * N_ + n0 + r] = 1.f / (1.f + expf(-dot));
    __syncthreads();

    #pragma unroll
    for (int i = 0; i < 8; ++i) {
        const int unit = i * 256 + t;
        const int d = unit >> 3, nch = (unit & 7) * 4;
        ushort4 wv;
        wv.x = lx[d][nch];     wv.y = lx[d][nch + 1];
        wv.z = lx[d][nch + 2]; wv.w = lx[d][nch + 3];
        *(ushort4*)(xT + ((size_t)b * D_ + d) * N_ + n0 + nch) = wv;
    }
}

// ---------------------------------------------------------------------------
// K3: dual-A MFMA GEMM: Ax = g*(A1@x) + (1-g)*(A2@x), then gcn-gate + x.
// Measured 4-wave shape (tile 32m x 256n, BK=32, grid 1024 flat + XCD swizzle)
// + T3/T4 counted-vmcnt pipeline: triple-buffered LDS (3 x 20KB), uniform
// 5 chunks/wave/iter, issue tile ks+2, steady wait vmcnt(5) BEFORE s_barrier
// (own retirement pre-barrier => cross-wave LDS visibility), never drain in
// main loop. T2 both-sides granule swizzle (16B granule ^= row bits1-2) on
// the GLOBAL SOURCE of global_load_lds (LDS linear) and on fragment reads.
__global__ __launch_bounds__(256, 2) void k_gemm_ax(
    const u16* __restrict__ depb, const u16* __restrict__ latb,
    const u16* __restrict__ depTb, const u16* __restrict__ latTb,
    const u16* __restrict__ xT,
    const float* __restrict__ gate,
    const float* __restrict__ Wgi, const float* __restrict__ Wgo,
    const float* __restrict__ bgi, const float* __restrict__ bgo,
    const float* __restrict__ xcur,
    u16* __restrict__ axin, u16* __restrict__ axout)
{
    // 3 x 20480B staging; epilogue aliases [32][260] f32 (33280B); tails @61440
    __shared__ __align__(16) char smem[61696];
    float* hbuf = (float*)smem;
    float* sh_g = (float*)(smem + 61440);
    float* sh_s = (float*)(smem + 61568);

    // bijective XCD swizzle: nwg=1024, 128/XCD; each XCD owns 2 full batches
    const int bid = blockIdx.x;
    const int logical = (bid & 7) * 128 + (bid >> 3);
    const int b = logical >> 6;
    const int rem = logical & 63;
    const int z = rem >> 5;
    const int m0 = (rem & 31) * 32;

    const u16* A1 = z ? depTb : depb;
    const u16* A2 = z ? latTb : latb;
    const float* Wg = z ? Wgo : Wgi;
    const float bg0 = z ? bgo[0] : bgi[0];
    u16* outp = z ? axout : axin;

    const int t = threadIdx.x;
    const int lane = t & 63;
    const int w = t >> 6;

    f32x4 acc1[2][4], acc2[2][4];
    const f32x4 fz = {0.f, 0.f, 0.f, 0.f};
    #pragma unroll
    for (int i = 0; i < 2; ++i)
        #pragma unroll
        for (int j = 0; j < 4; ++j) { acc1[i][j] = fz; acc2[i][j] = fz; }

    // 20 x 1KB chunks, 5/wave (uniform => exact per-wave vmcnt accounting).
    // Per chunk: row_local = lane>>2, granule = lane&3; source granule
    // pre-swizzled by row bits1-2 ((lane>>3)&3) so linear LDS dest holds
    // slot g at global granule g^xor(row).
    const u16* gsrc[5];
    int loff[5];
    const int rl = lane >> 2;
    const int kk = (((lane & 3) ^ ((lane >> 3) & 3)) << 3);
    #pragma unroll
    for (int ci = 0; ci < 5; ++ci) {
        const int c = w * 5 + ci;
        if (c < 4) {
            const int cc = c & 1;
            const int m = cc * 16 + rl;
            const u16* base = (c < 2) ? A1 : A2;
            gsrc[ci] = base + ((size_t)b * N_ + m0 + m) * N_ + kk;
            loff[ci] = ((c < 2) ? 0 : 1024) + cc * 512;
        } else {
            const int cc = c - 4;
            const int n = cc * 16 + rl;
            gsrc[ci] = xT + ((size_t)b * D_ + n) * N_ + kk;
            loff[ci] = 2048 + cc * 512;
        }
    }

    u16* const sb = (u16*)smem;   // 3 bufs x 10240 u16: [sA1 1024|sA2 1024|sB 8192]

    // prologue: stage tiles 0 and 1
    #pragma unroll
    for (int ci = 0; ci < 5; ++ci) gl_lds16(gsrc[ci], sb + loff[ci]);
    #pragma unroll
    for (int ci = 0; ci < 5; ++ci) { gl_lds16(gsrc[ci] + 32, sb + 10240 + loff[ci]); gsrc[ci] += 64; }

    const int mrow = lane & 15;
    const int kg = (((lane >> 4) ^ ((mrow >> 1) & 3)) << 3);  // swizzled read granule

    for (int ks = 0; ks < N_ / 32; ++ks) {
        if (ks == 31) vm_wait0(); else vm_wait5();   // retire tile ks (keep ks+1 in flight)
        __builtin_amdgcn_s_barrier();
        __builtin_amdgcn_sched_barrier(0);
        if (ks <= 29) {                              // issue tile ks+2 into buffer (ks+2)%3
            u16* nb = sb + ((ks + 2) % 3) * 10240;
            #pragma unroll
            for (int ci = 0; ci < 5; ++ci) { gl_lds16(gsrc[ci], nb + loff[ci]); gsrc[ci] += 32; }
        }
        const u16* cur = sb + (ks % 3) * 10240;
        const u16* sA1 = cur;
        const u16* sA2 = cur + 1024;
        const u16* sB  = cur + 2048;
        bf16x8 a1[2], a2[2], fb[4];
        #pragma unroll
        for (int mt = 0; mt < 2; ++mt) {
            const int row = mt * 16 + mrow;
            a1[mt] = *(const bf16x8*)(sA1 + row * 32 + kg);
            a2[mt] = *(const bf16x8*)(sA2 + row * 32 + kg);
        }
        #pragma unroll
        for (int nt = 0; nt < 4; ++nt) {
            const int row = w * 64 + nt * 16 + mrow;
            fb[nt] = *(const bf16x8*)(sB + row * 32 + kg);
        }
        #pragma unroll
        for (int mt = 0; mt < 2; ++mt)
            #pragma unroll
            for (int nt = 0; nt < 4; ++nt) {
                acc1[mt][nt] = __builtin_amdgcn_mfma_f32_16x16x32_bf16(a1[mt], fb[nt], acc1[mt][nt], 0, 0, 0);
                acc2[mt][nt] = __builtin_amdgcn_mfma_f32_16x16x32_bf16(a2[mt], fb[nt], acc2[mt][nt], 0, 0, 0);
            }
    }
    __syncthreads();   // all LDS reads done; safe to alias staging with hbuf

    if (t < 32) sh_g[t] = gate[(size_t)b * N_ + m0 + t];
    __syncthreads();

    // epilogue: gate blend into hbuf (C layout: col=lane&15, row=(lane>>4)*4+reg)
    const int hi = lane >> 4;
    #pragma unroll
    for (int mt = 0; mt < 2; ++mt)
        #pragma unroll
        for (int nt = 0; nt < 4; ++nt) {
            const int col = w * 64 + nt * 16 + mrow;
            #pragma unroll
            for (int rr = 0; rr < 4; ++rr) {
                const int row = mt * 16 + hi * 4 + rr;
                const float g = sh_g[row];
                hbuf[row * 260 + col] = g * acc1[mt][nt][rr] + (1.f - g) * acc2[mt][nt][rr];
            }
        }
    __syncthreads();

    {   // per-row dot with Wg -> sigmoid
        const int rr = t >> 3;
        const int c0 = (t & 7) * 32;
        float dot = 0.f;
        #pragma unroll 8
        for (int u = 0; u < 32; ++u) dot += hbuf[rr * 260 + c0 + u] * Wg[c0 + u];
        dot += __shfl_down(dot, 4, 8);
        dot += __shfl_down(dot, 2, 8);
        dot += __shfl_down(dot, 1, 8);
        if ((t & 7) == 0) sh_s[rr] = 1.f / (1.f + expf(-dot));
    }
    __syncthreads();

    #pragma unroll
    for (int i = 0; i < 16; ++i) {
        const int row = (t >> 7) + i * 2;
        const int c = (t & 127) * 2;
        const float s = sh_s[row];
        const size_t gidx = ((size_t)b * N_ + m0 + row) * D_ + c;
        const float2 xv = *(const float2*)(xcur + gidx);
        const float v0 = hbuf[row * 260 + c] * s + bg0 + xv.x;
        const float v1 = hbuf[row * 260 + c + 1] * s + bg0 + xv.y;
        *(ushort2*)(outp + gidx) = make_ushort2(f2bf(v0), f2bf(v1));
    }
}

// ---------------------------------------------------------------------------
// K4: h = [axin@Wi^T + 2bi, axout@Wo^T + 2bo]; LayerNorm; exact GELU.
// Same counted-vmcnt triple-buffer pipeline (8 K-steps). grid (N/32, B).
__global__ __launch_bounds__(256, 2) void k_fc_ln(
    const u16* __restrict__ axin, const u16* __restrict__ axout,
    const u16* __restrict__ Wib, const u16* __restrict__ Wob,
    const float* __restrict__ bi, const float* __restrict__ bo,
    const float* __restrict__ lg, const float* __restrict__ lb,
    float* __restrict__ outp)
{
    __shared__ __align__(16) char smem[61696];
    float* hbuf = (float*)smem;                 // epilogue alias [32][260]
    float* sh_mu = (float*)(smem + 61440);
    float* sh_rs = (float*)(smem + 61568);

    const int b = blockIdx.y, m0 = blockIdx.x * 32;
    const int t = threadIdx.x, lane = t & 63, w = t >> 6;
    const int half = w >> 1, wn = w & 1;

    f32x4 acc[2][4];
    const f32x4 fz = {0.f, 0.f, 0.f, 0.f};
    #pragma unroll
    for (int i = 0; i < 2; ++i)
        #pragma unroll
        for (int j = 0; j < 4; ++j) acc[i][j] = fz;

    // per-buffer layout (u16): sAin@0, sAout@1024, sWi@2048, sWo@6144
    const u16* gsrc[5];
    int loff[5];
    const int rl = lane >> 2;
    const int kk = (((lane & 3) ^ ((lane >> 3) & 3)) << 3);
    #pragma unroll
    for (int ci = 0; ci < 5; ++ci) {
        const int c = w * 5 + ci;
        if (c < 4) {
            const int cc = c & 1;
            const int m = cc * 16 + rl;
            const u16* base = (c < 2) ? axin : axout;
            gsrc[ci] = base + ((size_t)b * N_ + m0 + m) * D_ + kk;
            loff[ci] = ((c < 2) ? 0 : 1024) + cc * 512;
        } else {
            const int cc = (c - 4) & 7;
            const int n = cc * 16 + rl;
            const u16* base = (c < 12) ? Wib : Wob;
            gsrc[ci] = base + (size_t)n * D_ + kk;
            loff[ci] = ((c < 12) ? 2048 : 6144) + cc * 512;
        }
    }

    u16* const sb = (u16*)smem;   // 3 bufs x 10240 u16

    #pragma unroll
    for (int ci = 0; ci < 5; ++ci) gl_lds16(gsrc[ci], sb + loff[ci]);
    #pragma unroll
    for (int ci = 0; ci < 5; ++ci) { gl_lds16(gsrc[ci] + 32, sb + 10240 + loff[ci]); gsrc[ci] += 64; }

    const int mrow = lane & 15;
    const int kg = (((lane >> 4) ^ ((mrow >> 1) & 3)) << 3);

    for (int ks = 0; ks < D_ / 32; ++ks) {
        if (ks == 7) vm_wait0(); else vm_wait5();
        __builtin_amdgcn_s_barrier();
        __builtin_amdgcn_sched_barrier(0);
        if (ks <= 5) {
            u16* nb = sb + ((ks + 2) % 3) * 10240;
            #pragma unroll
            for (int ci = 0; ci < 5; ++ci) { gl_lds16(gsrc[ci], nb + loff[ci]); gsrc[ci] += 32; }
        }
        const u16* cur = sb + (ks % 3) * 10240;
        const u16* sA = cur + (half ? 1024 : 0);
        const u16* sW = cur + 2048 + (half ? 4096 : 0);
        bf16x8 a[2], fb[4];
        #pragma unroll
        for (int mt = 0; mt < 2; ++mt)
            a[mt] = *(const bf16x8*)(sA + (mt * 16 + mrow) * 32 + kg);
        #pragma unroll
        for (int nt = 0; nt < 4; ++nt)
            fb[nt] = *(const bf16x8*)(sW + (wn * 64 + nt * 16 + mrow) * 32 + kg);
        #pragma unroll
        for (int mt = 0; mt < 2; ++mt)
            #pragma unroll
            for (int nt = 0; nt < 4; ++nt)
                acc[mt][nt] = __builtin_amdgcn_mfma_f32_16x16x32_bf16(a[mt], fb[nt], acc[mt][nt], 0, 0, 0);
    }
    __syncthreads();

    const int hi = lane >> 4;
    #pragma unroll
    for (int mt = 0; mt < 2; ++mt)
        #pragma unroll
        for (int nt = 0; nt < 4; ++nt) {
            const int colh = wn * 64 + nt * 16 + mrow;
            const int col = half * 128 + colh;
            const float bias = 2.f * (half ? bo[colh] : bi[colh]);
            #pragma unroll
            for (int rr = 0; rr < 4; ++rr) {
                const int row = mt * 16 + hi * 4 + rr;
                hbuf[row * 260 + col] = acc[mt][nt][rr] + bias;
            }
        }
    __syncthreads();

    {   // LN stats per row
        const int rr = t >> 3;
        const int c0 = (t & 7) * 32;
        float s = 0.f, ss = 0.f;
        #pragma unroll 8
        for (int u = 0; u < 32; ++u) {
            const float v = hbuf[rr * 260 + c0 + u];
            s += v; ss += v * v;
        }
        s += __shfl_down(s, 4, 8);  ss += __shfl_down(ss, 4, 8);
        s += __shfl_down(s, 2, 8);  ss += __shfl_down(ss, 2, 8);
        s += __shfl_down(s, 1, 8);  ss += __shfl_down(ss, 1, 8);
        if ((t & 7) == 0) {
            const float mu = s * (1.f / 256.f);
            const float var = ss * (1.f / 256.f) - mu * mu;
            sh_mu[rr] = mu;
            sh_rs[rr] = rsqrtf(var + 1e-5f);
        }
    }
    __syncthreads();

    #pragma unroll
    for (int i = 0; i < 16; ++i) {
        const int row = (t >> 7) + i * 2;
        const int c = (t & 127) * 2;
        const float mu = sh_mu[row], rs = sh_rs[row];
        const float2 gg = *(const float2*)(lg + c);
        const float2 bb = *(const float2*)(lb + c);
        const float v0 = (hbuf[row * 260 + c] - mu) * rs * gg.x + bb.x;
        const float v1 = (hbuf[row * 260 + c + 1] - mu) * rs * gg.y + bb.y;
        const float y0 = 0.5f * v0 * (1.f + erff(v0 * 0.70710678118654752f));
        const float y1 = 0.5f * v1 * (1.f + erff(v1 * 0.70710678118654752f));
        const size_t gidx = ((size_t)b * N_ + m0 + row) * D_ + c;
        *(float2*)(outp + gidx) = make_float2(y0, y1);
    }
}

// ---------------------------------------------------------------------------
extern "C" void kernel_launch(void* const* d_in, const int* in_sizes, int n_in,
                              void* d_out, int out_size, void* d_ws, size_t ws_size,
                              hipStream_t stream)
{
    (void)in_sizes; (void)n_in; (void)out_size; (void)ws_size;

    const float* x0  = (const float*)d_in[0];
    const float* lat = (const float*)d_in[1];
    const float* dep = (const float*)d_in[2];
    const float* rg  = (const float*)d_in[3];
    const float* Wgi = (const float*)d_in[4];
    const float* bgi = (const float*)d_in[5];
    const float* Wgo = (const float*)d_in[6];
    const float* bgo = (const float*)d_in[7];
    const float* fiW = (const float*)d_in[8];
    const float* fib = (const float*)d_in[9];
    const float* foW = (const float*)d_in[10];
    const float* fob = (const float*)d_in[11];
    const float* lng = (const float*)d_in[12];
    const float* lnb = (const float*)d_in[13];

    char* ws = (char*)d_ws;
    size_t off = 0;
    auto alloc = [&](size_t bytes) {
        char* p = ws + off;
        off += (bytes + 255) & ~(size_t)255;
        return p;
    };
    u16* depb  = (u16*)alloc(2ull * B_ * N_ * N_);
    u16* latb  = (u16*)alloc(2ull * B_ * N_ * N_);
    u16* depTb = (u16*)alloc(2ull * B_ * N_ * N_);
    u16* latTb = (u16*)alloc(2ull * B_ * N_ * N_);
    u16* xT    = (u16*)alloc(2ull * B_ * D_ * N_);
    u16* axin  = (u16*)alloc(2ull * B_ * N_ * D_);
    u16* axout = (u16*)alloc(2ull * B_ * N_ * D_);
    float* gate = (float*)alloc(4ull * B_ * N_);
    float* xbuf = (float*)alloc(4ull * B_ * N_ * D_);
    u16* Wib = (u16*)alloc(2ull * H_ * D_);
    u16* Wob = (u16*)alloc(2ull * H_ * D_);

    k_conv_adj<<<dim3(16, 16, 32), 256, 0, stream>>>(dep, lat, depb, latb, depTb, latTb);

    const float* xcur = x0;
    for (int l = 0; l < 2; ++l) {
        k_gate_xt<<<dim3(32, B_ + 4), 256, 0, stream>>>(
            xcur, rg + l * D_, gate, xT,
            fiW + (size_t)l * H_ * D_, foW + (size_t)l * H_ * D_, Wib, Wob);
        k_gemm_ax<<<dim3(1024), 256, 0, stream>>>(
            depb, latb, depTb, latTb, xT, gate,
            Wgi + l * D_, Wgo + l * D_, bgi + l, bgo + l,
            xcur, axin, axout);
        const bool last = (l == 1);
        k_fc_ln<<<dim3(32, B_), 256, 0, stream>>>(
            axin, axout, Wib, Wob,
            fib + l * H_, fob + l * H_,
            lng + l * 2 * H_, lnb + l * 2 * H_,
            last ? (float*)d_out : xbuf);
        xcur = xbuf;
    }
}

// Round 6
// 321.005 us; speedup vs baseline: 1.1122x; 1.0984x over previous
//
#include <hip/hip_runtime.h>
#include <hip/hip_bf16.h>
#include <cstdint>

#define B_ 16
#define N_ 1024
#define D_ 256
#define H_ 128

typedef unsigned short u16;
typedef __attribute__((ext_vector_type(8))) short bf16x8;
typedef __attribute__((ext_vector_type(4))) float f32x4;

__device__ __forceinline__ u16 f2bf(float f) {
    union { float f; uint32_t u; } v; v.f = f;
    return (u16)((v.u + 0x7FFFu + ((v.u >> 16) & 1u)) >> 16);  // RNE
}
__device__ __forceinline__ float bf2f(u16 h) {
    union { uint32_t u; float f; } v; v.u = ((uint32_t)h) << 16;
    return v.f;
}

typedef __attribute__((address_space(3))) void lds_void;
typedef const __attribute__((address_space(1))) void g_void;

__device__ __forceinline__ void gl_lds16(const void* g, void* l) {
    __builtin_amdgcn_global_load_lds((g_void*)g, (lds_void*)l, 16, 0, 0);
}

__device__ __forceinline__ void vm_wait4() { asm volatile("s_waitcnt vmcnt(4)" ::: "memory"); }
__device__ __forceinline__ void vm_wait2() { asm volatile("s_waitcnt vmcnt(2)" ::: "memory"); }
__device__ __forceinline__ void vm_wait0() { asm volatile("s_waitcnt vmcnt(0)" ::: "memory"); }
__device__ __forceinline__ void lgkm0()   { asm volatile("s_waitcnt lgkmcnt(0)" ::: "memory"); }

// ---------------------------------------------------------------------------
// K1: fp32 adjacencies -> bf16 (normal + transposed). 64x64 tiles: every
// 4-lane group stores 128B contiguous segments for BOTH outputs.
__global__ __launch_bounds__(256) void k_conv_adj(
    const float* __restrict__ dep, const float* __restrict__ lat,
    u16* __restrict__ depb, u16* __restrict__ latb,
    u16* __restrict__ depTb, u16* __restrict__ latTb)
{
    __shared__ u16 tile[64][64];
    const int bz = blockIdx.z;
    const int b = bz >> 1;
    const float* src = (bz & 1) ? lat : dep;
    u16* dstN = (bz & 1) ? latb : depb;
    u16* dstT = (bz & 1) ? latTb : depTb;
    const int r0 = blockIdx.y * 64, c0 = blockIdx.x * 64;
    const int t = threadIdx.x;
    const int r = t >> 2, cg = (t & 3) * 16;

    const float* srow = src + ((size_t)b * N_ + r0 + r) * N_ + c0 + cg;
    bf16x8 lo, hi;
    {
        const float4 v0 = *(const float4*)(srow);
        const float4 v1 = *(const float4*)(srow + 4);
        const float4 v2 = *(const float4*)(srow + 8);
        const float4 v3 = *(const float4*)(srow + 12);
        lo[0] = (short)f2bf(v0.x); lo[1] = (short)f2bf(v0.y); lo[2] = (short)f2bf(v0.z); lo[3] = (short)f2bf(v0.w);
        lo[4] = (short)f2bf(v1.x); lo[5] = (short)f2bf(v1.y); lo[6] = (short)f2bf(v1.z); lo[7] = (short)f2bf(v1.w);
        hi[0] = (short)f2bf(v2.x); hi[1] = (short)f2bf(v2.y); hi[2] = (short)f2bf(v2.z); hi[3] = (short)f2bf(v2.w);
        hi[4] = (short)f2bf(v3.x); hi[5] = (short)f2bf(v3.y); hi[6] = (short)f2bf(v3.z); hi[7] = (short)f2bf(v3.w);
    }
    u16* nrow = dstN + ((size_t)b * N_ + r0 + r) * N_ + c0 + cg;
    *(bf16x8*)nrow = lo;
    *(bf16x8*)(nrow + 8) = hi;

    const int g0 = (t & 3) * 2;
    const int s = r & 7;
    *(bf16x8*)(&tile[r][((g0    ) ^ s) * 8]) = lo;
    *(bf16x8*)(&tile[r][((g0 + 1) ^ s) * 8]) = hi;
    __syncthreads();

    const int sc = t >> 2, rg2 = (t & 3) * 16;
    bf16x8 o0, o1;
    #pragma unroll
    for (int i = 0; i < 8; ++i) {
        const int R = rg2 + i;
        o0[i] = (short)tile[R][(((sc >> 3) ^ (R & 7)) * 8) + (sc & 7)];
    }
    #pragma unroll
    for (int i = 0; i < 8; ++i) {
        const int R = rg2 + 8 + i;
        o1[i] = (short)tile[R][(((sc >> 3) ^ (R & 7)) * 8) + (sc & 7)];
    }
    u16* dT = dstT + ((size_t)b * N_ + c0 + sc) * N_ + r0 + rg2;
    *(bf16x8*)dT = o0;
    *(bf16x8*)(dT + 8) = o1;
}

// ---------------------------------------------------------------------------
// K2: per-layer refine gate + x transposed to bf16 [B, D, N] (+ FC weight cvt)
__global__ __launch_bounds__(256) void k_gate_xt(
    const float* __restrict__ x, const float* __restrict__ rg,
    float* __restrict__ gate, u16* __restrict__ xT,
    const float* __restrict__ wi, const float* __restrict__ wo,
    u16* __restrict__ wib, u16* __restrict__ wob)
{
    if (blockIdx.y >= B_) {
        const int i = ((blockIdx.y - B_) * 32 + blockIdx.x) * 256 + threadIdx.x;
        wib[i] = f2bf(wi[i]);
        wob[i] = f2bf(wo[i]);
        return;
    }

    __shared__ u16 lx[D_][36];
    __shared__ float srg[D_];
    const int b = blockIdx.y, n0 = blockIdx.x * 32;
    const int t = threadIdx.x;
    srg[t] = rg[t];
    __syncthreads();

    const int r = t >> 3, cg = t & 7;
    const float* xrow = x + ((size_t)b * N_ + n0 + r) * D_;
    float dot = 0.f;
    #pragma unroll
    for (int u = 0; u < 8; ++u) {
        const int c = cg * 32 + u * 4;
        const float4 v = *(const float4*)(xrow + c);
        lx[c][r] = f2bf(v.x); lx[c + 1][r] = f2bf(v.y);
        lx[c + 2][r] = f2bf(v.z); lx[c + 3][r] = f2bf(v.w);
        dot += v.x * srg[c] + v.y * srg[c + 1] + v.z * srg[c + 2] + v.w * srg[c + 3];
    }
    dot += __shfl_down(dot, 4, 8);
    dot += __shfl_down(dot, 2, 8);
    dot += __shfl_down(dot, 1, 8);
    if (cg == 0) gate[(size_t)b * N_ + n0 + r] = 1.f / (1.f + expf(-dot));
    __syncthreads();

    #pragma unroll
    for (int i = 0; i < 8; ++i) {
        const int unit = i * 256 + t;
        const int d = unit >> 3, nch = (unit & 7) * 4;
        ushort4 wv;
        wv.x = lx[d][nch];     wv.y = lx[d][nch + 1];
        wv.z = lx[d][nch + 2]; wv.w = lx[d][nch + 3];
        *(ushort4*)(xT + ((size_t)b * D_ + d) * N_ + n0 + nch) = wv;
    }
}

// ---------------------------------------------------------------------------
// K3 v3: SINGLE blended GEMM. A_blend[m][k] = g[m]*A1[m][k] + (1-g[m])*A2[m][k]
// (per-row gate => blend commutes with the matmul; halves MFMA work vs dual).
// Tile 128m x 256n, BK=32, 8 waves (2x4, each 64x64, acc=64 f32). A reg-staged
// (issue ks+3, blend+ds_write ks+2); B via global_load_lds (issue ks+2).
// Counted vmcnt(4): retire B(ks+1), keep A(ks+3)+B(ks+2) in flight across the
// barriers. Grid 256 = exactly 1 block/CU; XCD-bijective swizzle by batch.
__global__ __launch_bounds__(512, 2) void k_gemm_ax(
    const u16* __restrict__ depb, const u16* __restrict__ latb,
    const u16* __restrict__ depTb, const u16* __restrict__ latTb,
    const u16* __restrict__ xT,
    const float* __restrict__ gate,
    const float* __restrict__ Wgi, const float* __restrict__ Wgo,
    const float* __restrict__ bgi, const float* __restrict__ bgo,
    const float* __restrict__ xcur,
    u16* __restrict__ axin, u16* __restrict__ axout)
{
    // 2 bufs x 24KB (A[128][32] 8KB + B[256][32] 16KB); epilogue hbuf aliases.
    __shared__ __align__(16) char smem[51712];
    u16* const sb = (u16*)smem;
    float* hbuf = (float*)smem;                 // [32][260] per store pass
    float* psum = (float*)(smem + 49152);       // [128][4]
    float* sh_s = (float*)(smem + 51200);       // [128]

    // bijective XCD swizzle: 256 blocks, 32/XCD; each XCD owns 2 full batches
    const int bid = blockIdx.x;
    const int logical = (bid & 7) * 32 + (bid >> 3);
    const int b = logical >> 4;
    const int rem = logical & 15;
    const int z = rem >> 3;
    const int m0 = (rem & 7) * 128;

    const u16* A1 = z ? depTb : depb;
    const u16* A2 = z ? latTb : latb;
    const float* Wg = z ? Wgo : Wgi;
    const float bg0 = z ? bgo[0] : bgi[0];
    u16* outp = z ? axout : axin;

    const int t = threadIdx.x;                  // 0..511
    const int lane = t & 63;
    const int w = t >> 6;                        // 0..7
    const int wr = w >> 2, wc = w & 3;           // wave tile (64m x 64n)

    // ---- A blend staging: thread t -> row t>>2, k-granule t&3 (8 bf16)
    const int arow = t >> 2;
    const int akq = t & 3;
    const float gv = gate[(size_t)b * N_ + m0 + arow];
    const u16* gA1 = A1 + ((size_t)b * N_ + m0 + arow) * N_ + akq * 8;
    const u16* gA2 = A2 + ((size_t)b * N_ + m0 + arow) * N_ + akq * 8;
    const int awoff = arow * 32 + ((akq ^ ((arow >> 1) & 3)) << 3);  // swizzled LDS slot

    // ---- B dma: 16 chunks of 16 rows; wave w stages chunks 2w, 2w+1.
    const int rl = lane >> 2;
    const int kk = (((lane & 3) ^ ((lane >> 3) & 3)) << 3);          // pre-swizzled src granule
    const u16* gB0 = xT + ((size_t)b * D_ + (w * 2) * 16 + rl) * N_ + kk;
    const u16* gB1 = xT + ((size_t)b * D_ + (w * 2 + 1) * 16 + rl) * N_ + kk;
    const int boff0 = 4096 + (w * 2) * 512;
    const int boff1 = 4096 + (w * 2 + 1) * 512;

    const int mrow = lane & 15;
    const int hi = lane >> 4;
    const int kg = (((lane >> 4) ^ ((mrow >> 1) & 3)) << 3);         // swizzled frag read

    f32x4 acc[4][4];
    const f32x4 fz = {0.f, 0.f, 0.f, 0.f};
    #pragma unroll
    for (int i = 0; i < 4; ++i)
        #pragma unroll
        for (int j = 0; j < 4; ++j) acc[i][j] = fz;

    bf16x8 rA1x, rA2x, rA1y, rA2y;

    auto blend_store = [&](const bf16x8& a1v, const bf16x8& a2v, u16* dst) {
        bf16x8 bl;
        #pragma unroll
        for (int u = 0; u < 8; ++u) {
            const float f1 = bf2f((u16)a1v[u]);
            const float f2 = bf2f((u16)a2v[u]);
            bl[u] = (short)f2bf(f2 + gv * (f1 - f2));
        }
        *(bf16x8*)dst = bl;
    };

    // ---- prologue: tiles 0,1 staged; A(2) regs in flight
    rA1x = *(const bf16x8*)(gA1);       rA2x = *(const bf16x8*)(gA2);
    blend_store(rA1x, rA2x, sb + awoff);                       // A(0) -> buf0
    rA1x = *(const bf16x8*)(gA1 + 32);  rA2x = *(const bf16x8*)(gA2 + 32);
    gl_lds16(gB0, sb + boff0);          gl_lds16(gB1, sb + boff1);          // B(0)
    blend_store(rA1x, rA2x, sb + 12288 + awoff);               // A(1) -> buf1
    rA1x = *(const bf16x8*)(gA1 + 64);  rA2x = *(const bf16x8*)(gA2 + 64);  // A(2) regs
    gl_lds16(gB0 + 32, sb + 12288 + boff0); gl_lds16(gB1 + 32, sb + 12288 + boff1); // B(1)
    vm_wait4();   // FIFO [B0x2, A2x2, B1x2] -> retire B(0) only
    lgkm0();
    __builtin_amdgcn_sched_barrier(0);
    __builtin_amdgcn_s_barrier();
    __builtin_amdgcn_sched_barrier(0);

    auto body = [&](int ks, bf16x8& c1, bf16x8& c2, bf16x8& n1, bf16x8& n2) {
        if (ks <= 28) {                                        // issue A(ks+3) regs
            n1 = *(const bf16x8*)(gA1 + (ks + 3) * 32);
            n2 = *(const bf16x8*)(gA2 + (ks + 3) * 32);
        }
        const u16* sA = sb + (ks & 1) * 12288;
        const u16* sBc = sA + 4096;
        bf16x8 a[4], fbv[4];
        #pragma unroll
        for (int mt = 0; mt < 4; ++mt)
            a[mt] = *(const bf16x8*)(sA + (wr * 64 + mt * 16 + mrow) * 32 + kg);
        #pragma unroll
        for (int nt = 0; nt < 4; ++nt)
            fbv[nt] = *(const bf16x8*)(sBc + (wc * 64 + nt * 16 + mrow) * 32 + kg);
        #pragma unroll
        for (int mt = 0; mt < 4; ++mt)
            #pragma unroll
            for (int nt = 0; nt < 4; ++nt)
                acc[mt][nt] = __builtin_amdgcn_mfma_f32_16x16x32_bf16(a[mt], fbv[nt], acc[mt][nt], 0, 0, 0);
        __builtin_amdgcn_sched_barrier(0);
        __builtin_amdgcn_s_barrier();       // all waves done reading cur
        __builtin_amdgcn_sched_barrier(0);
        if (ks <= 29) {                                        // tile ks+2 -> cur buffer
            u16* cb = sb + (ks & 1) * 12288;
            blend_store(c1, c2, cb + awoff);                   // implicit wait retires A(ks+2)
            gl_lds16(gB0 + (ks + 2) * 32, cb + boff0);
            gl_lds16(gB1 + (ks + 2) * 32, cb + boff1);
        }
        if (ks <= 28) vm_wait4();           // retire B(ks+1); keep A(ks+3)+B(ks+2)
        else if (ks == 29) vm_wait2();      // retire B(30); keep B(31)
        else if (ks == 30) vm_wait0();      // retire B(31)
        lgkm0();
        __builtin_amdgcn_sched_barrier(0);
        __builtin_amdgcn_s_barrier();
        __builtin_amdgcn_sched_barrier(0);
    };

    for (int kp = 0; kp < 16; ++kp) {
        body(2 * kp,     rA1x, rA2x, rA1y, rA2y);
        body(2 * kp + 1, rA1y, rA2y, rA1x, rA2x);
    }
    __syncthreads();

    // ---- gcn-gate: full-row dot from acc regs. Wg values for this lane's cols.
    float wgv[4];
    #pragma unroll
    for (int nt = 0; nt < 4; ++nt) wgv[nt] = Wg[wc * 64 + nt * 16 + mrow];
    #pragma unroll
    for (int mt = 0; mt < 4; ++mt) {
        #pragma unroll
        for (int rr = 0; rr < 4; ++rr) {
            float p = acc[mt][0][rr] * wgv[0] + acc[mt][1][rr] * wgv[1]
                    + acc[mt][2][rr] * wgv[2] + acc[mt][3][rr] * wgv[3];
            p += __shfl_xor(p, 1, 16);
            p += __shfl_xor(p, 2, 16);
            p += __shfl_xor(p, 4, 16);
            p += __shfl_xor(p, 8, 16);
            if (mrow == 0) psum[(wr * 64 + mt * 16 + hi * 4 + rr) * 4 + wc] = p;
        }
    }
    __syncthreads();
    if (t < 128) {
        const float d = psum[t * 4] + psum[t * 4 + 1] + psum[t * 4 + 2] + psum[t * 4 + 3];
        sh_s[t] = 1.f / (1.f + expf(-d));
    }
    __syncthreads();

    // ---- 4 store passes of 32 rows each (hbuf aliases staging; drained above)
    #pragma unroll
    for (int p = 0; p < 4; ++p) {
        if (wr == (p >> 1)) {
            #pragma unroll
            for (int mtl = 0; mtl < 2; ++mtl) {
                const int mt = (p & 1) * 2 + mtl;
                #pragma unroll
                for (int nt = 0; nt < 4; ++nt) {
                    const int col = wc * 64 + nt * 16 + mrow;
                    #pragma unroll
                    for (int rr = 0; rr < 4; ++rr) {
                        const int hrow = mtl * 16 + hi * 4 + rr;
                        hbuf[hrow * 260 + col] = acc[mt][nt][rr];
                    }
                }
            }
        }
        __syncthreads();
        {
            const int sr = t >> 4;                 // 0..31
            const int sc0 = (t & 15) * 16;
            const int grow = p * 32 + sr;
            const float s = sh_s[grow];
            const size_t gb = ((size_t)b * N_ + m0 + grow) * D_ + sc0;
            const float* xr = xcur + gb;
            u16* orow = outp + gb;
            bf16x8 o0, o1;
            #pragma unroll
            for (int u = 0; u < 8; ++u)
                o0[u] = (short)f2bf(hbuf[sr * 260 + sc0 + u] * s + bg0 + xr[u]);
            #pragma unroll
            for (int u = 0; u < 8; ++u)
                o1[u] = (short)f2bf(hbuf[sr * 260 + sc0 + 8 + u] * s + bg0 + xr[8 + u]);
            *(bf16x8*)orow = o0;
            *(bf16x8*)(orow + 8) = o1;
        }
        __syncthreads();
    }
}

// ---------------------------------------------------------------------------
// K4: h = [axin@Wi^T + 2bi, axout@Wo^T + 2bo]; LayerNorm; exact GELU.
// Counted-vmcnt triple-buffer pipeline (8 K-steps). grid (N/32, B).
__global__ __launch_bounds__(256, 2) void k_fc_ln(
    const u16* __restrict__ axin, const u16* __restrict__ axout,
    const u16* __restrict__ Wib, const u16* __restrict__ Wob,
    const float* __restrict__ bi, const float* __restrict__ bo,
    const float* __restrict__ lg, const float* __restrict__ lb,
    float* __restrict__ outp)
{
    __shared__ __align__(16) char smem[61696];
    float* hbuf = (float*)smem;
    float* sh_mu = (float*)(smem + 61440);
    float* sh_rs = (float*)(smem + 61568);

    const int b = blockIdx.y, m0 = blockIdx.x * 32;
    const int t = threadIdx.x, lane = t & 63, w = t >> 6;
    const int half = w >> 1, wn = w & 1;

    f32x4 acc[2][4];
    const f32x4 fz = {0.f, 0.f, 0.f, 0.f};
    #pragma unroll
    for (int i = 0; i < 2; ++i)
        #pragma unroll
        for (int j = 0; j < 4; ++j) acc[i][j] = fz;

    const u16* gsrc[5];
    int loff[5];
    const int rl = lane >> 2;
    const int kk = (((lane & 3) ^ ((lane >> 3) & 3)) << 3);
    #pragma unroll
    for (int ci = 0; ci < 5; ++ci) {
        const int c = w * 5 + ci;
        if (c < 4) {
            const int cc = c & 1;
            const int m = cc * 16 + rl;
            const u16* base = (c < 2) ? axin : axout;
            gsrc[ci] = base + ((size_t)b * N_ + m0 + m) * D_ + kk;
            loff[ci] = ((c < 2) ? 0 : 1024) + cc * 512;
        } else {
            const int cc = (c - 4) & 7;
            const int n = cc * 16 + rl;
            const u16* base = (c < 12) ? Wib : Wob;
            gsrc[ci] = base + (size_t)n * D_ + kk;
            loff[ci] = ((c < 12) ? 2048 : 6144) + cc * 512;
        }
    }

    u16* const sb = (u16*)smem;

    #pragma unroll
    for (int ci = 0; ci < 5; ++ci) gl_lds16(gsrc[ci], sb + loff[ci]);
    #pragma unroll
    for (int ci = 0; ci < 5; ++ci) { gl_lds16(gsrc[ci] + 32, sb + 10240 + loff[ci]); gsrc[ci] += 64; }

    const int mrow = lane & 15;
    const int kg = (((lane >> 4) ^ ((mrow >> 1) & 3)) << 3);

    for (int ks = 0; ks < D_ / 32; ++ks) {
        if (ks == 7) vm_wait0(); else { asm volatile("s_waitcnt vmcnt(5)" ::: "memory"); }
        __builtin_amdgcn_s_barrier();
        __builtin_amdgcn_sched_barrier(0);
        if (ks <= 5) {
            u16* nb = sb + ((ks + 2) % 3) * 10240;
            #pragma unroll
            for (int ci = 0; ci < 5; ++ci) { gl_lds16(gsrc[ci], nb + loff[ci]); gsrc[ci] += 32; }
        }
        const u16* cur = sb + (ks % 3) * 10240;
        const u16* sA = cur + (half ? 1024 : 0);
        const u16* sW = cur + 2048 + (half ? 4096 : 0);
        bf16x8 a[2], fb[4];
        #pragma unroll
        for (int mt = 0; mt < 2; ++mt)
            a[mt] = *(const bf16x8*)(sA + (mt * 16 + mrow) * 32 + kg);
        #pragma unroll
        for (int nt = 0; nt < 4; ++nt)
            fb[nt] = *(const bf16x8*)(sW + (wn * 64 + nt * 16 + mrow) * 32 + kg);
        #pragma unroll
        for (int mt = 0; mt < 2; ++mt)
            #pragma unroll
            for (int nt = 0; nt < 4; ++nt)
                acc[mt][nt] = __builtin_amdgcn_mfma_f32_16x16x32_bf16(a[mt], fb[nt], acc[mt][nt], 0, 0, 0);
    }
    __syncthreads();

    const int hi = lane >> 4;
    #pragma unroll
    for (int mt = 0; mt < 2; ++mt)
        #pragma unroll
        for (int nt = 0; nt < 4; ++nt) {
            const int colh = wn * 64 + nt * 16 + mrow;
            const int col = half * 128 + colh;
            const float bias = 2.f * (half ? bo[colh] : bi[colh]);
            #pragma unroll
            for (int rr = 0; rr < 4; ++rr) {
                const int row = mt * 16 + hi * 4 + rr;
                hbuf[row * 260 + col] = acc[mt][nt][rr] + bias;
            }
        }
    __syncthreads();

    {
        const int rr = t >> 3;
        const int c0 = (t & 7) * 32;
        float s = 0.f, ss = 0.f;
        #pragma unroll 8
        for (int u = 0; u < 32; ++u) {
            const float v = hbuf[rr * 260 + c0 + u];
            s += v; ss += v * v;
        }
        s += __shfl_down(s, 4, 8);  ss += __shfl_down(ss, 4, 8);
        s += __shfl_down(s, 2, 8);  ss += __shfl_down(ss, 2, 8);
        s += __shfl_down(s, 1, 8);  ss += __shfl_down(ss, 1, 8);
        if ((t & 7) == 0) {
            const float mu = s * (1.f / 256.f);
            const float var = ss * (1.f / 256.f) - mu * mu;
            sh_mu[rr] = mu;
            sh_rs[rr] = rsqrtf(var + 1e-5f);
        }
    }
    __syncthreads();

    #pragma unroll
    for (int i = 0; i < 16; ++i) {
        const int row = (t >> 7) + i * 2;
        const int c = (t & 127) * 2;
        const float mu = sh_mu[row], rs = sh_rs[row];
        const float2 gg = *(const float2*)(lg + c);
        const float2 bb = *(const float2*)(lb + c);
        const float v0 = (hbuf[row * 260 + c] - mu) * rs * gg.x + bb.x;
        const float v1 = (hbuf[row * 260 + c + 1] - mu) * rs * gg.y + bb.y;
        const float y0 = 0.5f * v0 * (1.f + erff(v0 * 0.70710678118654752f));
        const float y1 = 0.5f * v1 * (1.f + erff(v1 * 0.70710678118654752f));
        const size_t gidx = ((size_t)b * N_ + m0 + row) * D_ + c;
        *(float2*)(outp + gidx) = make_float2(y0, y1);
    }
}

// ---------------------------------------------------------------------------
extern "C" void kernel_launch(void* const* d_in, const int* in_sizes, int n_in,
                              void* d_out, int out_size, void* d_ws, size_t ws_size,
                              hipStream_t stream)
{
    (void)in_sizes; (void)n_in; (void)out_size; (void)ws_size;

    const float* x0  = (const float*)d_in[0];
    const float* lat = (const float*)d_in[1];
    const float* dep = (const float*)d_in[2];
    const float* rg  = (const float*)d_in[3];
    const float* Wgi = (const float*)d_in[4];
    const float* bgi = (const float*)d_in[5];
    const float* Wgo = (const float*)d_in[6];
    const float* bgo = (const float*)d_in[7];
    const float* fiW = (const float*)d_in[8];
    const float* fib = (const float*)d_in[9];
    const float* foW = (const float*)d_in[10];
    const float* fob = (const float*)d_in[11];
    const float* lng = (const float*)d_in[12];
    const float* lnb = (const float*)d_in[13];

    char* ws = (char*)d_ws;
    size_t off = 0;
    auto alloc = [&](size_t bytes) {
        char* p = ws + off;
        off += (bytes + 255) & ~(size_t)255;
        return p;
    };
    u16* depb  = (u16*)alloc(2ull * B_ * N_ * N_);
    u16* latb  = (u16*)alloc(2ull * B_ * N_ * N_);
    u16* depTb = (u16*)alloc(2ull * B_ * N_ * N_);
    u16* latTb = (u16*)alloc(2ull * B_ * N_ * N_);
    u16* xT    = (u16*)alloc(2ull * B_ * D_ * N_);
    u16* axin  = (u16*)alloc(2ull * B_ * N_ * D_);
    u16* axout = (u16*)alloc(2ull * B_ * N_ * D_);
    float* gate = (float*)alloc(4ull * B_ * N_);
    float* xbuf = (float*)alloc(4ull * B_ * N_ * D_);
    u16* Wib = (u16*)alloc(2ull * H_ * D_);
    u16* Wob = (u16*)alloc(2ull * H_ * D_);

    k_conv_adj<<<dim3(16, 16, 32), 256, 0, stream>>>(dep, lat, depb, latb, depTb, latTb);

    const float* xcur = x0;
    for (int l = 0; l < 2; ++l) {
        k_gate_xt<<<dim3(32, B_ + 4), 256, 0, stream>>>(
            xcur, rg + l * D_, gate, xT,
            fiW + (size_t)l * H_ * D_, foW + (size_t)l * H_ * D_, Wib, Wob);
        k_gemm_ax<<<dim3(256), 512, 0, stream>>>(
            depb, latb, depTb, latTb, xT, gate,
            Wgi + l * D_, Wgo + l * D_, bgi + l, bgo + l,
            xcur, axin, axout);
        const bool last = (l == 1);
        k_fc_ln<<<dim3(32, B_), 256, 0, stream>>>(
            axin, axout, Wib, Wob,
            fib + l * H_, fob + l * H_,
            lng + l * 2 * H_, lnb + l * 2 * H_,
            last ? (float*)d_out : xbuf);
        xcur = xbuf;
    }
}